// Round 2
// 1135.251 us; speedup vs baseline: 1.0137x; 1.0137x over previous
//
#include <hip/hip_runtime.h>

// LinearRegressionHospi: per-batch OLS fit over last W=30 timesteps of feature 0,
// extrapolate NF=14 steps. B=1e6, T=60, F=4, fp32.
//
// Memory-bound: needed bytes = 480 B/batch read (16B feature stride forces the
// whole 480B span to be fetched) + 56 B/batch write. Roofline ~90 us at 6.3 TB/s.
//
// R2 = R1 with the launcher size units fixed (in_sizes/out_size are ELEMENT
// counts, not bytes -- R1 divided by 4x too much, B=250k, 3/4 of output unwritten).
//  - Phase 1 uses __builtin_amdgcn_global_load_lds width=4 (async, fire-and-forget,
//    no VGPR round-trip, no per-load vmcnt stall; HBM line traffic identical).
//  - res[] overlaid onto y[] after the fit-read barrier: LDS 46080 -> 30720 B
//    => 5 blocks/CU (20 waves/CU, 62.5% occupancy) vs 3 blocks/CU (37%).
//  - y layout is linear [batch*30 + t] (gload_lds writes lane-ordered contiguous);
//    phase-2 stride-30 rows are 4-way bank conflicted on a minor phase -- accepted.

#define NBATCH 256   // batches per block (== blockDim.x)
#define W      30    // window_size
#define NF     14    // n_forecast
#define TDIM   60    // T

typedef const __attribute__((address_space(1))) void gvoid_t;
typedef __attribute__((address_space(3))) void lvoid_t;

__global__ __launch_bounds__(256)
void linreg_forecast_kernel(const float* __restrict__ in,
                            float4* __restrict__ out4,
                            int B, int out4_total)
{
    // y: 256 batches x 30 timesteps, linear. res (256*14 floats = 14336 B) is
    // overlaid onto the front of y after the fit phase. Total LDS = 30720 B.
    __shared__ __align__(16) float y[NBATCH * W];

    const int tid = threadIdx.x;
    const int B0  = blockIdx.x * NBATCH;

    // ---- Phase 1: async global->LDS of y[i] = inputs[B0 + i/30, 30 + i%30, 0] ----
    // i = tid + 256k over [0, 7680): consecutive lanes -> consecutive t within a
    // batch -> each 64B line serves 4 lanes (stride-16B dword gather), fetched once.
    #pragma unroll
    for (int k = 0; k < W; ++k) {
        int i  = tid + (k << 8);
        int bb = i / W;                    // magic-mul division
        int t  = i - bb * W;
        int gb = B0 + bb;
        if (gb > B - 1) gb = B - 1;        // clamp: duplicate loads, never OOB
        const float* src = in + ((size_t)(gb * TDIM + W + t) << 2);  // feature 0
        // LDS dest is wave-uniform base + lane*4; &y[i] is lane-ordered contiguous.
        __builtin_amdgcn_global_load_lds((gvoid_t*)src, (lvoid_t*)&y[i], 4, 0, 0);
    }
    __syncthreads();   // compiler drains vmcnt(0) before s_barrier

    // ---- Phase 2a: per-thread OLS fit for batch B0+tid (reads y only) ----
    float slope, intercept;
    {
        const float* row = &y[tid * W];
        float s0 = 0.f, s1 = 0.f;
        #pragma unroll
        for (int t = 0; t < W; ++t) {
            float v = row[t];
            s0 += v;
            s1 += v * ((float)t - 14.5f);    // xc = t - x_mean
        }
        // sxx = sum((t-14.5)^2, t=0..29) = 2247.5
        slope     = s1 * (1.0f / 2247.5f);
        intercept = s0 * (1.0f / 30.0f) - slope * 14.5f;
    }
    __syncthreads();   // all reads of y complete before res overlays it

    // ---- Phase 2b: write forecasts into the reused LDS buffer ----
    {
        int gb = B0 + tid;
        if (gb < B) {
            float* r = &y[tid * NF];
            #pragma unroll
            for (int j = 0; j < NF; ++j)
                r[j] = intercept + slope * (float)(W + j);  // t_future = 30..43
        }
    }
    __syncthreads();

    // ---- Phase 3: coalesced float4 store of this block's 3584 outputs ----
    const int base4 = blockIdx.x * (NBATCH * NF / 4);   // 896 float4 / block
    const float4* res4 = (const float4*)y;
    #pragma unroll
    for (int k = 0; k < 4; ++k) {
        int i = tid + (k << 8);
        if (i < NBATCH * NF / 4 && base4 + i < out4_total)
            out4[base4 + i] = res4[i];
    }
}

extern "C" void kernel_launch(void* const* d_in, const int* in_sizes, int n_in,
                              void* d_out, int out_size, void* d_ws, size_t ws_size,
                              hipStream_t stream)
{
    const float* in = (const float*)d_in[0];
    float*      out = (float*)d_out;
    int B = in_sizes[0] / (TDIM * 4);          // element count: 240e6/240 = 1,000,000
    int grid = (B + NBATCH - 1) / NBATCH;      // 3907 blocks
    linreg_forecast_kernel<<<grid, 256, 0, stream>>>(
        in, (float4*)out, B, out_size / 4);
}

// Round 3
// 1123.817 us; speedup vs baseline: 1.0240x; 1.0102x over previous
//
#include <hip/hip_runtime.h>

// LinearRegressionHospi: per-batch OLS fit over last W=30 timesteps of feature 0,
// extrapolate NF=14 steps. B=1e6, T=60, F=4, fp32.
//
// Forced-fetch roofline: feature-0 dwords at 16B stride -> whole 480 B/batch span
// fetched = 480 MB read + 56 MB write ~= 90 us at 6.3 TB/s.
//
// R3: discriminating experiment. R0 (sync LDS, 37% occ) == R2 (async gload_lds,
// 62% occ) == ~1135-1150 us total => phase-1 style and occupancy are NOT the
// lever. This version removes every remaining structural suspect:
//   - NO LDS, NO barriers, NO vmcnt(0) block-wide drain.
//   - 32 lanes per batch (lane = timestep): one float4 load per lane; a wave
//     covers 2 adjacent batches = two contiguous 480 B runs (same 480 MB line
//     set as before, still fetched exactly once).
//   - segmented butterfly __shfl_xor (masks 1,2,4,8,16 stay inside 32-lane
//     groups) reduces s0 = sum(y), s1 = sum(y*(t-14.5)) in-register.
//   - all 32 lanes get s0,s1; lanes 0..13 store the 14 forecasts directly.
//     Wave stores 28 dwords over one contiguous 112 B span; block's 8 batches
//     form one contiguous 448 B output run. L2 merges partial lines.
//   - 0 B LDS, ~24 VGPR -> 8 blocks/CU = 32 waves/CU = 100% occupancy.
// If this STILL times ~1135: three maximally-different structures tie ->
// timed region is harness-floored (3.84 GB re-poison fills ~610 us each) and
// the kernel is at its forced-fetch roofline.

#define W    30    // window_size
#define NF   14    // n_forecast
#define TDIM 60    // T
#define BPB  8     // batches per 256-thread block (32 lanes per batch)

__global__ __launch_bounds__(256)
void linreg_forecast_kernel(const float4* __restrict__ in4,
                            float* __restrict__ out,
                            int B)
{
    const int tid  = threadIdx.x;
    const int lane = tid & 31;                 // timestep index within batch
    const int b    = blockIdx.x * BPB + (tid >> 5);
    const int gb   = (b < B) ? b : (B - 1);    // clamp: dup loads, never OOB

    // ---- load: y_t = inputs[gb, 30+t, 0]; lanes 30,31 clamp to t=29 (masked) ----
    const int t = (lane < W) ? lane : (W - 1);
    float4 v = in4[(size_t)gb * TDIM + W + t];
    float  y = (lane < W) ? v.x : 0.0f;

    // ---- segmented (32-lane) butterfly reduction of s0, s1 ----
    float s0 = y;
    float s1 = y * ((float)t - 14.5f);         // xc = t - x_mean; t clamped but y=0 there
    #pragma unroll
    for (int m = 1; m <= 16; m <<= 1) {
        s0 += __shfl_xor(s0, m);
        s1 += __shfl_xor(s1, m);
    }

    // sxx = sum((t-14.5)^2, t=0..29) = 2247.5 ; x_mean = 14.5
    const float slope     = s1 * (1.0f / 2247.5f);
    const float intercept = s0 * (1.0f / 30.0f) - slope * 14.5f;

    // ---- store: lanes 0..13 write forecast j = lane; t_future = 30..43 ----
    if (lane < NF && b < B)
        out[b * NF + lane] = intercept + slope * (float)(W + lane);
}

extern "C" void kernel_launch(void* const* d_in, const int* in_sizes, int n_in,
                              void* d_out, int out_size, void* d_ws, size_t ws_size,
                              hipStream_t stream)
{
    const float* in = (const float*)d_in[0];
    float*      out = (float*)d_out;
    int B = in_sizes[0] / (TDIM * 4);          // element count: 240e6/240 = 1,000,000
    int grid = (B + BPB - 1) / BPB;            // 125,000 blocks
    linreg_forecast_kernel<<<grid, 256, 0, stream>>>(
        (const float4*)in, out, B);
}